// Round 5
// baseline (583.237 us; speedup 1.0000x reference)
//
#include <hip/hip_runtime.h>
#include <cstdint>

// ---------------------------------------------------------------------------
// MultiHeadAttention (B=8,S=1024,D=1024,H=16,E=64). Inputs fp32, output fp32.
// Quirks: scale = 1/sqrt(8) (d_k = batch quirk); tril + exact-zero -> -1e9
// (fp32, pre-round); softmax over HEADS axis (local per (b,q,k)).
//
// R12: attack the measured ~55% barrier-lockstep idle (all pipes <20% busy)
// with TWO independent blocks per CU:
//  - scf stored as bf16 (R1-R6-proven; all-masked rows still exact 1/16
//    since all entries equal) -> LDS 110.6KB -> 75.8KB -> 2 blocks/CU,
//    softmax LDS traffic halved.
//  - R11's two per-block tasks split into two separate blocks (grid 512,
//    half=id>>8). All 512 co-resident (32 waves/CU, VGPR<=64 enforced via
//    launch_bounds(1024,8); R11 measured exactly 64). Co-resident blocks
//    have uncorrelated barriers -> phases interleave, idle is shared.
//  - inner loop = R7/R11 verbatim (no lambdas/dbuf — those spilled in
//    R8/R10); balanced k-split front/back halves; fp32 unsafeAtomicAdd
//    into zeroed P (2 commutative contributors, deterministic); uniform
//    tail (k>q => all heads masked => attn==1/16) on the back-half block;
//    b=id&7==XCD (K/V L2 locality, FETCH 139->65MB win).
// ---------------------------------------------------------------------------

typedef unsigned short u16;
typedef unsigned int   u32;
typedef __attribute__((ext_vector_type(8))) __bf16         bf16x8;
typedef __attribute__((ext_vector_type(8))) unsigned short ushort8;
typedef __attribute__((ext_vector_type(4))) float          f32x4;

#define S_ 1024
#define D_ 1024
#define H_ 16
#define E_ 64

__device__ __forceinline__ float b2f(u16 h) {
  union { u32 u; float f; } v; v.u = ((u32)h) << 16; return v.f;
}
__device__ __forceinline__ u16 f2b(float f) {      // round-to-nearest-even
  union { float f; u32 u; } v; v.f = f;
  u32 r = v.u + 0x7fffu + ((v.u >> 16) & 1u);
  return (u16)(r >> 16);
}

typedef const __attribute__((address_space(1))) u32 gu32;
typedef       __attribute__((address_space(3))) u32 lu32;

// 16B global->LDS direct load; LDS dest must be wave-uniform base + lane*16.
__device__ __forceinline__ void gload_lds16(const u16* g, u16* l) {
  __builtin_amdgcn_global_load_lds((gu32*)(uintptr_t)g, (lu32*)(uintptr_t)l,
                                   16, 0, 0);
}

// ---------------------------------------------------------------------------
// fp32 -> bf16 elementwise convert (n = multiple of 2048).
// ---------------------------------------------------------------------------
__global__ __launch_bounds__(256, 1) void cvt_bf16(
    const float* __restrict__ src, u16* __restrict__ dst)
{
  const size_t i = (size_t)blockIdx.x * 256 + threadIdx.x;
  float4 a = ((const float4*)src)[2 * i];
  float4 b = ((const float4*)src)[2 * i + 1];
  ushort8 o;
  o[0] = f2b(a.x); o[1] = f2b(a.y); o[2] = f2b(a.z); o[3] = f2b(a.w);
  o[4] = f2b(b.x); o[5] = f2b(b.y); o[6] = f2b(b.z); o[7] = f2b(b.w);
  ((ushort8*)dst)[i] = o;
}

// ---------------------------------------------------------------------------
// Weight transpose+convert: W fp32 [K][N] -> Wt bf16 [N][K]. 64x64 tiles.
// ---------------------------------------------------------------------------
__global__ __launch_bounds__(256, 1) void trans_cvt_w(
    const float* __restrict__ W, u16* __restrict__ Wt)
{
  __shared__ u16 t[64][72];
  const int k0 = blockIdx.x * 64, n0 = blockIdx.y * 64;
  const int row = threadIdx.x >> 3;
  const int cs  = (threadIdx.x & 7) * 8;
#pragma unroll
  for (int p = 0; p < 2; ++p) {
    int r = row + p * 32;
    const float* Wp = W + (size_t)(k0 + r) * 1024 + n0 + cs;
    float4 a = *(const float4*)(Wp);
    float4 b = *(const float4*)(Wp + 4);
    u16* tp = &t[r][cs];
    tp[0] = f2b(a.x); tp[1] = f2b(a.y); tp[2] = f2b(a.z); tp[3] = f2b(a.w);
    tp[4] = f2b(b.x); tp[5] = f2b(b.y); tp[6] = f2b(b.z); tp[7] = f2b(b.w);
  }
  __syncthreads();
#pragma unroll
  for (int p = 0; p < 2; ++p) {
    int n = row + p * 32;
    ushort8 v;
#pragma unroll
    for (int i = 0; i < 8; ++i) v[i] = t[cs + i][n];
    *(ushort8*)(Wt + (size_t)(n0 + n) * 1024 + k0 + cs) = v;
  }
}

// ---------------------------------------------------------------------------
// bf16 MFMA GEMM: C[M][N] = A[M][K] @ Bt[N][K]^T + bias[N] (fp32 accum).
// 128x128 tile, BK=32, 256 threads / 4 waves. m97-style global_load_lds
// width-16 staging. out_f32: 1 -> fp32 stores, 0 -> bf16 stores.
// ---------------------------------------------------------------------------
__global__ __launch_bounds__(256, 1) void gemm_bf16(
    const u16* __restrict__ A, const u16* __restrict__ Bt,
    const float* __restrict__ bias, void* __restrict__ Cv,
    int M, int N, int K, int out_f32)
{
  __shared__ u16 As[128 * 32];   // [m][k] row-major, 8KB
  __shared__ u16 Bs[128 * 32];   // [n][k] row-major, 8KB
  const int tid  = threadIdx.x;
  const int wave = tid >> 6;
  const int lane = tid & 63;
  const int quad = lane >> 4;
  const int l16  = lane & 15;
  const int m0   = (wave & 1) * 64;
  const int n0   = (wave >> 1) * 64;

  const u16* Ab = A  + (size_t)blockIdx.x * 128 * K;
  const u16* Bb = Bt + (size_t)blockIdx.y * 128 * K;

  f32x4 acc[4][4];
#pragma unroll
  for (int i = 0; i < 4; ++i)
#pragma unroll
    for (int j = 0; j < 4; ++j) acc[i][j] = (f32x4){0.f, 0.f, 0.f, 0.f};

  for (int kb = 0; kb < K; kb += 32) {
    __syncthreads();               // prior iter's LDS reads done
#pragma unroll
    for (int p = 0; p < 2; ++p) {  // 512 16B segs over 256 threads
      int seg = tid + p * 256;     // = (wave*64+p*256) + lane -> base+lane*16
      int row = seg >> 2, ks = seg & 3;
      gload_lds16(Ab + (size_t)row * K + kb + ks * 8, As + seg * 8);
      gload_lds16(Bb + (size_t)row * K + kb + ks * 8, Bs + seg * 8);
    }
    __builtin_amdgcn_s_waitcnt(0); // drain vmcnt before barrier
    __syncthreads();

    bf16x8 af[4], bfr[4];
#pragma unroll
    for (int i = 0; i < 4; ++i)    // A-frag: m=lane&15, k=quad*8+j
      af[i] = *(const bf16x8*)(As + (m0 + i * 16 + l16) * 32 + quad * 8);
#pragma unroll
    for (int j = 0; j < 4; ++j)    // B-frag: n=lane&15, k=quad*8+j
      bfr[j] = *(const bf16x8*)(Bs + (n0 + j * 16 + l16) * 32 + quad * 8);
#pragma unroll
    for (int i = 0; i < 4; ++i)
#pragma unroll
      for (int j = 0; j < 4; ++j)
        acc[i][j] = __builtin_amdgcn_mfma_f32_16x16x32_bf16(
            af[i], bfr[j], acc[i][j], 0, 0, 0);
  }

  float bv[4];
#pragma unroll
  for (int j = 0; j < 4; ++j)
    bv[j] = bias[(size_t)blockIdx.y * 128 + n0 + j * 16 + l16];

  if (out_f32) {
    float* C = (float*)Cv;
#pragma unroll
    for (int i = 0; i < 4; ++i) {
      int r = blockIdx.x * 128 + m0 + i * 16 + quad * 4;   // row=quad*4+reg
#pragma unroll
      for (int j = 0; j < 4; ++j) {
        int c = blockIdx.y * 128 + n0 + j * 16 + l16;      // col=lane&15
#pragma unroll
        for (int reg = 0; reg < 4; ++reg)
          C[(size_t)(r + reg) * N + c] = acc[i][j][reg] + bv[j];
      }
    }
  } else {
    u16* C = (u16*)Cv;
#pragma unroll
    for (int i = 0; i < 4; ++i) {
      int r = blockIdx.x * 128 + m0 + i * 16 + quad * 4;
#pragma unroll
      for (int j = 0; j < 4; ++j) {
        int c = blockIdx.y * 128 + n0 + j * 16 + l16;
#pragma unroll
        for (int reg = 0; reg < 4; ++reg)
          C[(size_t)(r + reg) * N + c] = f2b(acc[i][j][reg] + bv[j]);
      }
    }
  }
}

// ---------------------------------------------------------------------------
// V transpose (bf16): V[b][s][h*64+e] -> Vt[(b*16+h)*64+e][s]  (per-head E,S)
// ---------------------------------------------------------------------------
__global__ __launch_bounds__(256, 1) void transpose_v(
    const u16* __restrict__ V, u16* __restrict__ Vt)
{
  __shared__ u16 t[64][72];
  const int s0 = blockIdx.x * 64;
  const int bh = blockIdx.y;           // b*16 + h
  const int b = bh >> 4, h = bh & 15;
  const int row = threadIdx.x >> 3;
  const int cs  = (threadIdx.x & 7) * 8;
#pragma unroll
  for (int p = 0; p < 2; ++p) {
    int s = row + p * 32;
    *(ushort8*)(&t[s][cs]) = *(const ushort8*)(
        V + ((size_t)(b * S_ + s0 + s)) * D_ + h * E_ + cs);
  }
  __syncthreads();
#pragma unroll
  for (int p = 0; p < 2; ++p) {
    int e = row + p * 32;
    ushort8 v;
#pragma unroll
    for (int i = 0; i < 8; ++i) v[i] = t[cs + i][e];
    *(ushort8*)(Vt + ((size_t)(bh * E_ + e)) * S_ + s0 + cs) = v;
  }
}

// ---------------------------------------------------------------------------
// Fused attention, softmax over HEADS, bf16 MFMA.  R12:
// R7's 32-q-row/1024-thread/16-warp/3-barrier inner loop; grid 512: block
// (b, j, half) does front (half=0) or back (half=1, +tail) k-range of its
// q-tile.  scf bf16 -> LDS 75.8KB -> 2 blocks/CU, all 512 co-resident;
// independent barriers overlap the lockstep idle.  Partials -> fp32
// unsafeAtomicAdd into zeroed P (2 contributors/elem, deterministic).
// LDS: scf[16][32][34] u16 (34.8KB) + at[16][32][40] u16 (41KB) = 75.8KB.
// ---------------------------------------------------------------------------
__global__ __launch_bounds__(1024, 8) void attn_headsoftmax(
    const u16* __restrict__ Qg,   // [B][S][D] bf16
    const u16* __restrict__ Kg,   // [B][S][D] bf16
    const u16* __restrict__ Vt,   // [B*H][E][S] bf16
    float* __restrict__ P)        // [B][S][D] fp32, zeroed
{
  const int id   = blockIdx.x;         // 0..511; id&7 == b == XCD
  const int b    = id & 7;
  const int half = id >> 8;            // 0: front k-half; 1: back k-half
  const int j    = (id & 255) >> 3;    // 0..31
  const int qt   = half ? (31 - j) : j;
  const int tid  = threadIdx.x;
  const int h    = tid >> 6;
  const int lane = tid & 63;
  const int quad = lane >> 4;
  const int l16  = lane & 15;
  const int q0   = qt * 32;

  const int hcut = (qt + 2) >> 1;            // ceil((qt+1)/2)
  const int ktLo = half ? hcut : 0;
  const int ktHi = half ? qt : (hcut - 1);   // inclusive

  __shared__ u16 scf[16][32][34];      // bf16 scores (34.8 KB)
  __shared__ u16 at[16][32][40];       // bf16 attn for PV A-frags (41 KB)

  const u16* Kh = Kg + (size_t)b * S_ * D_ + h * E_;
  const u16* Vh = Vt + ((size_t)(b * H_ + h) * E_) * S_;

  // 1/sqrt(8), correctly rounded fp32; s==0 <=> dot==0 under both forms.
  const float inv_rsq8 = 0.35355339059327373f;

  // ---- Q fragments (R7 verbatim) ----
  bf16x8 qf[2][2];
  {
    const u16* Qb = Qg + ((size_t)(b * S_ + q0)) * D_ + h * E_;
#pragma unroll
    for (int i = 0; i < 2; ++i)
#pragma unroll
      for (int c = 0; c < 2; ++c)
        qf[i][c] = *(const bf16x8*)(Qb + (size_t)(i * 16 + l16) * D_ +
                                    c * 32 + quad * 8);
  }

  f32x4 oacc[2][4];
#pragma unroll
  for (int i = 0; i < 2; ++i)
#pragma unroll
    for (int nc = 0; nc < 4; ++nc) oacc[i][nc] = (f32x4){0.f, 0.f, 0.f, 0.f};

  for (int kt = ktLo; kt <= ktHi; ++kt) {
    const int k0 = kt * 32;
    {  // ---- scores = Q K^T * (1/sqrt8), mask, -> LDS bf16 ----
      const u16* Kb = Kh + (size_t)k0 * D_;
      bf16x8 kf[2][2];
#pragma unroll
      for (int nc = 0; nc < 2; ++nc)
#pragma unroll
        for (int c = 0; c < 2; ++c)
          kf[nc][c] = *(const bf16x8*)(Kb + (size_t)(nc * 16 + l16) * D_ +
                                       c * 32 + quad * 8);
      f32x4 sacc[2][2];
#pragma unroll
      for (int i = 0; i < 2; ++i)
#pragma unroll
        for (int nc = 0; nc < 2; ++nc)
          sacc[i][nc] = (f32x4){0.f, 0.f, 0.f, 0.f};
#pragma unroll
      for (int c = 0; c < 2; ++c)
#pragma unroll
        for (int i = 0; i < 2; ++i)
#pragma unroll
          for (int nc = 0; nc < 2; ++nc)
            sacc[i][nc] = __builtin_amdgcn_mfma_f32_16x16x32_bf16(
                qf[i][c], kf[nc][c], sacc[i][nc], 0, 0, 0);
#pragma unroll
      for (int i = 0; i < 2; ++i)
#pragma unroll
        for (int nc = 0; nc < 2; ++nc)
#pragma unroll
          for (int reg = 0; reg < 4; ++reg) {
            int qrow = i * 16 + quad * 4 + reg;  // C: row=quad*4+reg
            int kcol = nc * 16 + l16;            // C: col=lane&15
            float s = sacc[i][nc][reg] * inv_rsq8;
            if ((k0 + kcol > q0 + qrow) || (s == 0.0f)) s = -1e9f;
            scf[h][qrow][kcol] = f2b(s);
          }
    }
    __syncthreads();
    {  // ---- softmax across 16 heads at this thread's (q,k) ----
      const int qq = tid >> 5, kk = tid & 31;
      float v[16];
      float m = -3.0e38f;
#pragma unroll
      for (int hh = 0; hh < 16; ++hh) {
        v[hh] = b2f(scf[hh][qq][kk]);
        m = fmaxf(m, v[hh]);
      }
      float sum = 0.f;
#pragma unroll
      for (int hh = 0; hh < 16; ++hh) {
        v[hh] = __expf(v[hh] - m);   // exp(0)=1, exp(-1e9)=0 exact
        sum += v[hh];
      }
      float inv = 1.0f / sum;        // all-masked: 1/16 (pow2) -> exact
#pragma unroll
      for (int hh = 0; hh < 16; ++hh) at[hh][qq][kk] = f2b(v[hh] * inv);
    }
    __syncthreads();
    {  // ---- O += attn @ V (R7 verbatim: V loaded inline) ----
      bf16x8 af[2];
#pragma unroll
      for (int i = 0; i < 2; ++i)    // A: m=q (lane&15), k=s (quad*8+jj)
        af[i] = *(const bf16x8*)(&at[h][i * 16 + l16][quad * 8]);
      const u16* Vb = Vh + k0;
      bf16x8 vf[4];
#pragma unroll
      for (int nc = 0; nc < 4; ++nc) // B: n=e (lane&15), k=s (quad*8+jj)
        vf[nc] = *(const bf16x8*)(Vb + (size_t)(nc * 16 + l16) * S_ +
                                  quad * 8);
#pragma unroll
      for (int i = 0; i < 2; ++i)
#pragma unroll
        for (int nc = 0; nc < 4; ++nc)
          oacc[i][nc] = __builtin_amdgcn_mfma_f32_16x16x32_bf16(
              af[i], vf[nc], oacc[i][nc], 0, 0, 0);
    }
    __syncthreads();
  }

  // ---- uniform tail (half==1 only): k >= (qt+1)*32 -> all heads masked ->
  // attn = 1/16 exactly; add (1/16) * sum_{s>=s0u} V[h][e][s].
  float suf[4] = {0.f, 0.f, 0.f, 0.f};
  if (half == 1) {
    const int s0u = (qt + 1) * 32;
    if (s0u < S_) {
      const int chunk = (S_ - s0u) >> 2;   // per-quad share, multiple of 8
#pragma unroll
      for (int nc = 0; nc < 4; ++nc) {
        const u16* vp = Vh + (size_t)(nc * 16 + l16) * S_ + s0u +
                        quad * chunk;
        float a = 0.f;
        for (int s = 0; s < chunk; s += 8) {
          ushort8 v8 = *(const ushort8*)(vp + s);
#pragma unroll
          for (int jj = 0; jj < 8; ++jj) a += b2f(v8[jj]);
        }
        suf[nc] = a;
      }
#pragma unroll
      for (int nc = 0; nc < 4; ++nc) {
        float a = suf[nc];
        a += __shfl_xor(a, 16);      // reduce across quad bits
        a += __shfl_xor(a, 32);
        suf[nc] = a * 0.0625f;       // * 1/16 (exact)
      }
    }
  }

  // ---- epilogue: accumulate partial into P (2 contributors/elem) ----
  float* Pb = P + ((size_t)(b * S_ + q0)) * D_ + h * E_;
#pragma unroll
  for (int i = 0; i < 2; ++i)
#pragma unroll
    for (int nc = 0; nc < 4; ++nc)
#pragma unroll
      for (int reg = 0; reg < 4; ++reg) {
        int qrow = i * 16 + quad * 4 + reg;
        int e    = nc * 16 + l16;
        unsafeAtomicAdd(&Pb[(size_t)qrow * D_ + e],
                        oacc[i][nc][reg] + suf[nc]);
      }
}

// ---------------------------------------------------------------------------
extern "C" void kernel_launch(void* const* d_in, const int* in_sizes, int n_in,
                              void* d_out, int out_size, void* d_ws,
                              size_t ws_size, hipStream_t stream)
{
  const float* X1 = (const float*)d_in[0];
  const float* X2 = (const float*)d_in[1];
  const float* Wq = (const float*)d_in[2];
  const float* bq = (const float*)d_in[3];
  const float* Wk = (const float*)d_in[4];
  const float* bk = (const float*)d_in[5];
  const float* Wv = (const float*)d_in[6];
  const float* bv = (const float*)d_in[7];
  const float* Wo = (const float*)d_in[8];
  const float* bo = (const float*)d_in[9];

  // Workspace (u16 units): X1b,X2b 8M each; Wt 1M x4; Qb,Kb,Vb,Vtb 8M each.
  // P (fp32 partial O, 32MB) aliases X1b+X2b (dead after QKV GEMMs).
  // AOb (bf16, 16MB) aliases Vb (dead after transpose_v). Total 88MB.
  u16* X1b = (u16*)d_ws;
  u16* X2b = X1b + (8u << 20);
  u16* WtQ = X2b + (8u << 20);
  u16* WtK = WtQ + (1u << 20);
  u16* WtV = WtK + (1u << 20);
  u16* WtO = WtV + (1u << 20);
  u16* Qb  = WtO + (1u << 20);
  u16* Kb  = Qb + (8u << 20);
  u16* Vb  = Kb + (8u << 20);
  u16* Vtb = Vb + (8u << 20);
  float* P = (float*)d_ws;   // 8192*1024 fp32 = 32MB = X1b+X2b region
  u16* AOb = Vb;             // alias

  cvt_bf16<<<4096, 256, 0, stream>>>(X1, X1b);
  cvt_bf16<<<4096, 256, 0, stream>>>(X2, X2b);

  dim3 tg(16, 16);
  trans_cvt_w<<<tg, 256, 0, stream>>>(Wq, WtQ);
  trans_cvt_w<<<tg, 256, 0, stream>>>(Wk, WtK);
  trans_cvt_w<<<tg, 256, 0, stream>>>(Wv, WtV);
  trans_cvt_w<<<tg, 256, 0, stream>>>(Wo, WtO);

  dim3 gg(64, 8);  // (M/128, N/128)
  gemm_bf16<<<gg, 256, 0, stream>>>(X1b, WtQ, bq, Qb, 8192, 1024, 1024, 0);
  gemm_bf16<<<gg, 256, 0, stream>>>(X2b, WtK, bk, Kb, 8192, 1024, 1024, 0);
  gemm_bf16<<<gg, 256, 0, stream>>>(X2b, WtV, bv, Vb, 8192, 1024, 1024, 0);

  transpose_v<<<dim3(16, 128), 256, 0, stream>>>(Vb, Vtb);

  // X1b/X2b dead now; zero P over their region, then accumulate partials.
  hipMemsetAsync(P, 0, (size_t)8192 * 1024 * 4, stream);

  attn_headsoftmax<<<dim3(512), 1024, 0, stream>>>(Qb, Kb, Vtb, P);

  cvt_bf16<<<4096, 256, 0, stream>>>(P, AOb);   // fp32 partial-sum -> bf16

  // Output fp32 (reference returns float32).
  gemm_bf16<<<gg, 256, 0, stream>>>(AOb, WtO, bo, d_out, 8192, 1024, 1024, 1);
}

// Round 6
// 440.577 us; speedup vs baseline: 1.3238x; 1.3238x over previous
//
#include <hip/hip_runtime.h>
#include <cstdint>

// ---------------------------------------------------------------------------
// MultiHeadAttention (B=8,S=1024,D=1024,H=16,E=64). Inputs fp32, output fp32.
// Quirks: scale = 1/sqrt(8) (d_k = batch quirk); tril + exact-zero -> -1e9
// (fp32, pre-round); softmax over HEADS axis (local per (b,q,k)).
//
// R13: R7's proven structure, KVBLK 32 -> 64 (halve barrier count).
//  Evidence ladder: R7 = 5.67us/iter x 32 iters (VGPR=60, clean). R8/R10/R12
//  all spilled when chasing occupancy (launch-bounds strangulation). R9
//  showed per-iter cost is ~independent of tile work (16-row tiles: same
//  cost/iter, half work) -> iteration idle is the cost driver. R11 showed
//  triangle+atomics overhead (+23us) exceeds its saving vs R7.
//  => keep R7's phases/registers byte-for-byte, run each phase body twice
//  per iteration (two 32-col k-sub-tiles), 3 barriers per 64 cols instead
//  of per 32. scf stored bf16 (R12-proven numerics) to fit LDS: 141KB.
//  1-D grid 256, b=id&7 (XCD=batch -> K/V L2-resident, R9's FETCH win).
//  No triangle, no atomics, no memset: attn writes bf16 AO directly.
// ---------------------------------------------------------------------------

typedef unsigned short u16;
typedef unsigned int   u32;
typedef __attribute__((ext_vector_type(8))) __bf16         bf16x8;
typedef __attribute__((ext_vector_type(8))) unsigned short ushort8;
typedef __attribute__((ext_vector_type(4))) float          f32x4;

#define S_ 1024
#define D_ 1024
#define H_ 16
#define E_ 64

__device__ __forceinline__ float b2f(u16 h) {
  union { u32 u; float f; } v; v.u = ((u32)h) << 16; return v.f;
}
__device__ __forceinline__ u16 f2b(float f) {      // round-to-nearest-even
  union { float f; u32 u; } v; v.f = f;
  u32 r = v.u + 0x7fffu + ((v.u >> 16) & 1u);
  return (u16)(r >> 16);
}

typedef const __attribute__((address_space(1))) u32 gu32;
typedef       __attribute__((address_space(3))) u32 lu32;

// 16B global->LDS direct load; LDS dest must be wave-uniform base + lane*16.
__device__ __forceinline__ void gload_lds16(const u16* g, u16* l) {
  __builtin_amdgcn_global_load_lds((gu32*)(uintptr_t)g, (lu32*)(uintptr_t)l,
                                   16, 0, 0);
}

// ---------------------------------------------------------------------------
// fp32 -> bf16 elementwise convert (n = multiple of 2048).
// ---------------------------------------------------------------------------
__global__ __launch_bounds__(256, 1) void cvt_bf16(
    const float* __restrict__ src, u16* __restrict__ dst)
{
  const size_t i = (size_t)blockIdx.x * 256 + threadIdx.x;
  float4 a = ((const float4*)src)[2 * i];
  float4 b = ((const float4*)src)[2 * i + 1];
  ushort8 o;
  o[0] = f2b(a.x); o[1] = f2b(a.y); o[2] = f2b(a.z); o[3] = f2b(a.w);
  o[4] = f2b(b.x); o[5] = f2b(b.y); o[6] = f2b(b.z); o[7] = f2b(b.w);
  ((ushort8*)dst)[i] = o;
}

// ---------------------------------------------------------------------------
// Weight transpose+convert: W fp32 [K][N] -> Wt bf16 [N][K]. 64x64 tiles.
// ---------------------------------------------------------------------------
__global__ __launch_bounds__(256, 1) void trans_cvt_w(
    const float* __restrict__ W, u16* __restrict__ Wt)
{
  __shared__ u16 t[64][72];
  const int k0 = blockIdx.x * 64, n0 = blockIdx.y * 64;
  const int row = threadIdx.x >> 3;
  const int cs  = (threadIdx.x & 7) * 8;
#pragma unroll
  for (int p = 0; p < 2; ++p) {
    int r = row + p * 32;
    const float* Wp = W + (size_t)(k0 + r) * 1024 + n0 + cs;
    float4 a = *(const float4*)(Wp);
    float4 b = *(const float4*)(Wp + 4);
    u16* tp = &t[r][cs];
    tp[0] = f2b(a.x); tp[1] = f2b(a.y); tp[2] = f2b(a.z); tp[3] = f2b(a.w);
    tp[4] = f2b(b.x); tp[5] = f2b(b.y); tp[6] = f2b(b.z); tp[7] = f2b(b.w);
  }
  __syncthreads();
#pragma unroll
  for (int p = 0; p < 2; ++p) {
    int n = row + p * 32;
    ushort8 v;
#pragma unroll
    for (int i = 0; i < 8; ++i) v[i] = t[cs + i][n];
    *(ushort8*)(Wt + (size_t)(n0 + n) * 1024 + k0 + cs) = v;
  }
}

// ---------------------------------------------------------------------------
// bf16 MFMA GEMM: C[M][N] = A[M][K] @ Bt[N][K]^T + bias[N] (fp32 accum).
// 128x128 tile, BK=32, 256 threads / 4 waves. m97-style global_load_lds
// width-16 staging. out_f32: 1 -> fp32 stores, 0 -> bf16 stores.
// ---------------------------------------------------------------------------
__global__ __launch_bounds__(256, 1) void gemm_bf16(
    const u16* __restrict__ A, const u16* __restrict__ Bt,
    const float* __restrict__ bias, void* __restrict__ Cv,
    int M, int N, int K, int out_f32)
{
  __shared__ u16 As[128 * 32];   // [m][k] row-major, 8KB
  __shared__ u16 Bs[128 * 32];   // [n][k] row-major, 8KB
  const int tid  = threadIdx.x;
  const int wave = tid >> 6;
  const int lane = tid & 63;
  const int quad = lane >> 4;
  const int l16  = lane & 15;
  const int m0   = (wave & 1) * 64;
  const int n0   = (wave >> 1) * 64;

  const u16* Ab = A  + (size_t)blockIdx.x * 128 * K;
  const u16* Bb = Bt + (size_t)blockIdx.y * 128 * K;

  f32x4 acc[4][4];
#pragma unroll
  for (int i = 0; i < 4; ++i)
#pragma unroll
    for (int j = 0; j < 4; ++j) acc[i][j] = (f32x4){0.f, 0.f, 0.f, 0.f};

  for (int kb = 0; kb < K; kb += 32) {
    __syncthreads();               // prior iter's LDS reads done
#pragma unroll
    for (int p = 0; p < 2; ++p) {  // 512 16B segs over 256 threads
      int seg = tid + p * 256;     // = (wave*64+p*256) + lane -> base+lane*16
      int row = seg >> 2, ks = seg & 3;
      gload_lds16(Ab + (size_t)row * K + kb + ks * 8, As + seg * 8);
      gload_lds16(Bb + (size_t)row * K + kb + ks * 8, Bs + seg * 8);
    }
    __builtin_amdgcn_s_waitcnt(0); // drain vmcnt before barrier
    __syncthreads();

    bf16x8 af[4], bfr[4];
#pragma unroll
    for (int i = 0; i < 4; ++i)    // A-frag: m=lane&15, k=quad*8+j
      af[i] = *(const bf16x8*)(As + (m0 + i * 16 + l16) * 32 + quad * 8);
#pragma unroll
    for (int j = 0; j < 4; ++j)    // B-frag: n=lane&15, k=quad*8+j
      bfr[j] = *(const bf16x8*)(Bs + (n0 + j * 16 + l16) * 32 + quad * 8);
#pragma unroll
    for (int i = 0; i < 4; ++i)
#pragma unroll
      for (int j = 0; j < 4; ++j)
        acc[i][j] = __builtin_amdgcn_mfma_f32_16x16x32_bf16(
            af[i], bfr[j], acc[i][j], 0, 0, 0);
  }

  float bv[4];
#pragma unroll
  for (int j = 0; j < 4; ++j)
    bv[j] = bias[(size_t)blockIdx.y * 128 + n0 + j * 16 + l16];

  if (out_f32) {
    float* C = (float*)Cv;
#pragma unroll
    for (int i = 0; i < 4; ++i) {
      int r = blockIdx.x * 128 + m0 + i * 16 + quad * 4;   // row=quad*4+reg
#pragma unroll
      for (int j = 0; j < 4; ++j) {
        int c = blockIdx.y * 128 + n0 + j * 16 + l16;      // col=lane&15
#pragma unroll
        for (int reg = 0; reg < 4; ++reg)
          C[(size_t)(r + reg) * N + c] = acc[i][j][reg] + bv[j];
      }
    }
  } else {
    u16* C = (u16*)Cv;
#pragma unroll
    for (int i = 0; i < 4; ++i) {
      int r = blockIdx.x * 128 + m0 + i * 16 + quad * 4;
#pragma unroll
      for (int j = 0; j < 4; ++j) {
        int c = blockIdx.y * 128 + n0 + j * 16 + l16;
#pragma unroll
        for (int reg = 0; reg < 4; ++reg)
          C[(size_t)(r + reg) * N + c] = f2b(acc[i][j][reg] + bv[j]);
      }
    }
  }
}

// ---------------------------------------------------------------------------
// V transpose (bf16): V[b][s][h*64+e] -> Vt[(b*16+h)*64+e][s]  (per-head E,S)
// ---------------------------------------------------------------------------
__global__ __launch_bounds__(256, 1) void transpose_v(
    const u16* __restrict__ V, u16* __restrict__ Vt)
{
  __shared__ u16 t[64][72];
  const int s0 = blockIdx.x * 64;
  const int bh = blockIdx.y;           // b*16 + h
  const int b = bh >> 4, h = bh & 15;
  const int row = threadIdx.x >> 3;
  const int cs  = (threadIdx.x & 7) * 8;
#pragma unroll
  for (int p = 0; p < 2; ++p) {
    int s = row + p * 32;
    *(ushort8*)(&t[s][cs]) = *(const ushort8*)(
        V + ((size_t)(b * S_ + s0 + s)) * D_ + h * E_ + cs);
  }
  __syncthreads();
#pragma unroll
  for (int p = 0; p < 2; ++p) {
    int e = row + p * 32;
    ushort8 v;
#pragma unroll
    for (int i = 0; i < 8; ++i) v[i] = t[cs + i][e];
    *(ushort8*)(Vt + ((size_t)(bh * E_ + e)) * S_ + s0 + cs) = v;
  }
}

// ---------------------------------------------------------------------------
// Fused attention, softmax over HEADS, bf16 MFMA.  R13:
// R7's 32-q-row/1024-thread/16-warp loop with KVBLK=64: each phase body runs
// twice (two 32-col k-sub-tiles) between barriers -> 16 iterations, 3
// barriers each (was 32). scf bf16. 1-D grid 256, b=id&7 (XCD locality).
// LDS: scf[16][32][66] u16 (66KB) + at[16][32][72] u16 (72KB) = 141.3KB.
// ---------------------------------------------------------------------------
__global__ __launch_bounds__(1024, 4) void attn_headsoftmax(
    const u16* __restrict__ Qg,   // [B][S][D] bf16
    const u16* __restrict__ Kg,   // [B][S][D] bf16
    const u16* __restrict__ Vt,   // [B*H][E][S] bf16
    u16* __restrict__ AO)         // [B][S][D] bf16
{
  const int id   = blockIdx.x;         // 0..255; id&7 == b == XCD
  const int b    = id & 7;
  const int qt   = id >> 3;            // 0..31
  const int tid  = threadIdx.x;
  const int h    = tid >> 6;
  const int lane = tid & 63;
  const int quad = lane >> 4;
  const int l16  = lane & 15;
  const int q0   = qt * 32;

  __shared__ u16 scf[16][32][66];      // bf16 scores, 64 cols + pad
  __shared__ u16 at[16][32][72];       // bf16 attn, 64 cols + pad (16B-align)

  const u16* Kh = Kg + (size_t)b * S_ * D_ + h * E_;
  const u16* Vh = Vt + ((size_t)(b * H_ + h) * E_) * S_;

  // 1/sqrt(8), correctly rounded fp32; s==0 <=> dot==0 under both forms.
  const float inv_rsq8 = 0.35355339059327373f;

  // ---- Q fragments (R7 verbatim) ----
  bf16x8 qf[2][2];
  {
    const u16* Qb = Qg + ((size_t)(b * S_ + q0)) * D_ + h * E_;
#pragma unroll
    for (int i = 0; i < 2; ++i)
#pragma unroll
      for (int c = 0; c < 2; ++c)
        qf[i][c] = *(const bf16x8*)(Qb + (size_t)(i * 16 + l16) * D_ +
                                    c * 32 + quad * 8);
  }

  f32x4 oacc[2][4];
#pragma unroll
  for (int i = 0; i < 2; ++i)
#pragma unroll
    for (int nc = 0; nc < 4; ++nc) oacc[i][nc] = (f32x4){0.f, 0.f, 0.f, 0.f};

  for (int kt = 0; kt < 16; ++kt) {
    const int k0 = kt * 64;
    // ---- QK^T: two 32-col sub-tiles, same registers reused (R7 profile) --
#pragma unroll
    for (int c2 = 0; c2 < 2; ++c2) {
      const int ks0 = k0 + c2 * 32;
      const u16* Kb = Kh + (size_t)ks0 * D_;
      bf16x8 kf[2][2];
#pragma unroll
      for (int nc = 0; nc < 2; ++nc)
#pragma unroll
        for (int c = 0; c < 2; ++c)
          kf[nc][c] = *(const bf16x8*)(Kb + (size_t)(nc * 16 + l16) * D_ +
                                       c * 32 + quad * 8);
      f32x4 sacc[2][2];
#pragma unroll
      for (int i = 0; i < 2; ++i)
#pragma unroll
        for (int nc = 0; nc < 2; ++nc)
          sacc[i][nc] = (f32x4){0.f, 0.f, 0.f, 0.f};
#pragma unroll
      for (int c = 0; c < 2; ++c)
#pragma unroll
        for (int i = 0; i < 2; ++i)
#pragma unroll
          for (int nc = 0; nc < 2; ++nc)
            sacc[i][nc] = __builtin_amdgcn_mfma_f32_16x16x32_bf16(
                qf[i][c], kf[nc][c], sacc[i][nc], 0, 0, 0);
#pragma unroll
      for (int i = 0; i < 2; ++i)
#pragma unroll
        for (int nc = 0; nc < 2; ++nc)
#pragma unroll
          for (int reg = 0; reg < 4; ++reg) {
            int qrow = i * 16 + quad * 4 + reg;  // C: row=quad*4+reg
            int kcol = nc * 16 + l16;            // C: col=lane&15
            float s = sacc[i][nc][reg] * inv_rsq8;
            if ((ks0 + kcol > q0 + qrow) || (s == 0.0f)) s = -1e9f;
            scf[h][qrow][c2 * 32 + kcol] = f2b(s);
          }
    }
    __syncthreads();
    {  // ---- softmax across 16 heads; 2 (q,k) points per thread ----
      const int qq = tid >> 5, kk = tid & 31;
#pragma unroll
      for (int c2 = 0; c2 < 2; ++c2) {
        const int kk2 = c2 * 32 + kk;
        float v[16];
        float m = -3.0e38f;
#pragma unroll
        for (int hh = 0; hh < 16; ++hh) {
          v[hh] = b2f(scf[hh][qq][kk2]);
          m = fmaxf(m, v[hh]);
        }
        float sum = 0.f;
#pragma unroll
        for (int hh = 0; hh < 16; ++hh) {
          v[hh] = __expf(v[hh] - m);   // exp(0)=1, exp(-1e9)=0 exact
          sum += v[hh];
        }
        float inv = 1.0f / sum;        // all-masked: 1/16 (pow2) -> exact
#pragma unroll
        for (int hh = 0; hh < 16; ++hh) at[hh][qq][kk2] = f2b(v[hh] * inv);
      }
    }
    __syncthreads();
    // ---- PV: two 32-col sub-tiles, same registers reused ----
#pragma unroll
    for (int c2 = 0; c2 < 2; ++c2) {
      bf16x8 af[2];
#pragma unroll
      for (int i = 0; i < 2; ++i)    // A: m=q (lane&15), k=s (quad*8+jj)
        af[i] = *(const bf16x8*)(&at[h][i * 16 + l16][c2 * 32 + quad * 8]);
      const u16* Vb = Vh + k0 + c2 * 32;
      bf16x8 vf[4];
#pragma unroll
      for (int nc = 0; nc < 4; ++nc) // B: n=e (lane&15), k=s (quad*8+jj)
        vf[nc] = *(const bf16x8*)(Vb + (size_t)(nc * 16 + l16) * S_ +
                                  quad * 8);
#pragma unroll
      for (int i = 0; i < 2; ++i)
#pragma unroll
        for (int nc = 0; nc < 4; ++nc)
          oacc[i][nc] = __builtin_amdgcn_mfma_f32_16x16x32_bf16(
              af[i], vf[nc], oacc[i][nc], 0, 0, 0);
    }
    __syncthreads();
  }

  u16* Ob = AO + ((size_t)(b * S_ + q0)) * D_ + h * E_;
#pragma unroll
  for (int i = 0; i < 2; ++i)
#pragma unroll
    for (int nc = 0; nc < 4; ++nc)
#pragma unroll
      for (int reg = 0; reg < 4; ++reg) {
        int qrow = i * 16 + quad * 4 + reg;
        int e    = nc * 16 + l16;
        Ob[(size_t)qrow * D_ + e] = f2b(oacc[i][nc][reg]);
      }
}

// ---------------------------------------------------------------------------
extern "C" void kernel_launch(void* const* d_in, const int* in_sizes, int n_in,
                              void* d_out, int out_size, void* d_ws,
                              size_t ws_size, hipStream_t stream)
{
  const float* X1 = (const float*)d_in[0];
  const float* X2 = (const float*)d_in[1];
  const float* Wq = (const float*)d_in[2];
  const float* bq = (const float*)d_in[3];
  const float* Wk = (const float*)d_in[4];
  const float* bk = (const float*)d_in[5];
  const float* Wv = (const float*)d_in[6];
  const float* bv = (const float*)d_in[7];
  const float* Wo = (const float*)d_in[8];
  const float* bo = (const float*)d_in[9];

  // Workspace (u16 units): X1b,X2b 8M; Wt 1M x4; Qb,Kb,Vb,Vtb 8M. AO aliases
  // Vb (dead after transpose_v). Total 44M u16 = 88MB.
  u16* X1b = (u16*)d_ws;
  u16* X2b = X1b + (8u << 20);
  u16* WtQ = X2b + (8u << 20);
  u16* WtK = WtQ + (1u << 20);
  u16* WtV = WtK + (1u << 20);
  u16* WtO = WtV + (1u << 20);
  u16* Qb  = WtO + (1u << 20);
  u16* Kb  = Qb + (8u << 20);
  u16* Vb  = Kb + (8u << 20);
  u16* Vtb = Vb + (8u << 20);
  u16* AOb = Vb;  // alias

  cvt_bf16<<<4096, 256, 0, stream>>>(X1, X1b);
  cvt_bf16<<<4096, 256, 0, stream>>>(X2, X2b);

  dim3 tg(16, 16);
  trans_cvt_w<<<tg, 256, 0, stream>>>(Wq, WtQ);
  trans_cvt_w<<<tg, 256, 0, stream>>>(Wk, WtK);
  trans_cvt_w<<<tg, 256, 0, stream>>>(Wv, WtV);
  trans_cvt_w<<<tg, 256, 0, stream>>>(Wo, WtO);

  dim3 gg(64, 8);  // (M/128, N/128)
  gemm_bf16<<<gg, 256, 0, stream>>>(X1b, WtQ, bq, Qb, 8192, 1024, 1024, 0);
  gemm_bf16<<<gg, 256, 0, stream>>>(X2b, WtK, bk, Kb, 8192, 1024, 1024, 0);
  gemm_bf16<<<gg, 256, 0, stream>>>(X2b, WtV, bv, Vb, 8192, 1024, 1024, 0);

  transpose_v<<<dim3(16, 128), 256, 0, stream>>>(Vb, Vtb);

  attn_headsoftmax<<<dim3(256), 1024, 0, stream>>>(Qb, Kb, Vtb, AOb);

  // Output fp32 (reference returns float32).
  gemm_bf16<<<gg, 256, 0, stream>>>(AOb, WtO, bo, d_out, 8192, 1024, 1024, 1);
}

// Round 7
// 434.187 us; speedup vs baseline: 1.3433x; 1.0147x over previous
//
#include <hip/hip_runtime.h>
#include <cstdint>

// ---------------------------------------------------------------------------
// MultiHeadAttention (B=8,S=1024,D=1024,H=16,E=64). Inputs fp32, output fp32.
// Quirks: scale = 1/sqrt(8) (d_k = batch quirk); tril + exact-zero -> -1e9
// (fp32, pre-round); softmax over HEADS axis (local per (b,q,k)).
//
// R14: surgical softmax-phase rework on R13's proven skeleton.
//  Evidence: R13 == R7 time (barrier count irrelevant). Per-iter budget:
//  MFMA 7.5%, VALU 34%, softmax LDS-issue ~6-8k cy (1024 scalar u16
//  wave-ops + 5.2M bank conflicts) -> softmax phase is LDS+VALU bound.
//  Changes (attn kernel only):
//   (1) softmax repartition: thread = (q, 2 consecutive k) -> all LDS
//       traffic becomes b32, conflict-free (64 lanes/32 banks 2-way).
//   (2) mask is head-INDEPENDENT (tril+zero-quirk): k>q points skip exp
//       entirely -> write bf16(1/16)=0x3D80. Block-uniformly masked QK
//       sub-tiles skipped wholesale (no K loads / MFMA / scf writes).
//   (3) no max-subtraction (scores O(10), fp32-safe; sum==0 guard for
//       the all-quirk case) + explicit tree sum -> serial chain 16->4.
//   (4) 2 barriers/iter (post-PV barrier redundant: PV reads `at`,
//       next QK writes `scf`; next post-QK barrier orders `at` reuse).
//  Register discipline (R8/R10/R12 lesson): no lambdas, no runtime-indexed
//  arrays; softmax live set ~55 regs + 48 persistent < 128 cap at 16 waves.
// ---------------------------------------------------------------------------

typedef unsigned short u16;
typedef unsigned int   u32;
typedef __attribute__((ext_vector_type(8))) __bf16         bf16x8;
typedef __attribute__((ext_vector_type(8))) unsigned short ushort8;
typedef __attribute__((ext_vector_type(4))) float          f32x4;

#define S_ 1024
#define D_ 1024
#define H_ 16
#define E_ 64

__device__ __forceinline__ float b2f(u16 h) {
  union { u32 u; float f; } v; v.u = ((u32)h) << 16; return v.f;
}
__device__ __forceinline__ u16 f2b(float f) {      // round-to-nearest-even
  union { float f; u32 u; } v; v.f = f;
  u32 r = v.u + 0x7fffu + ((v.u >> 16) & 1u);
  return (u16)(r >> 16);
}

typedef const __attribute__((address_space(1))) u32 gu32;
typedef       __attribute__((address_space(3))) u32 lu32;

// 16B global->LDS direct load; LDS dest must be wave-uniform base + lane*16.
__device__ __forceinline__ void gload_lds16(const u16* g, u16* l) {
  __builtin_amdgcn_global_load_lds((gu32*)(uintptr_t)g, (lu32*)(uintptr_t)l,
                                   16, 0, 0);
}

// ---------------------------------------------------------------------------
// fp32 -> bf16 elementwise convert (n = multiple of 2048).
// ---------------------------------------------------------------------------
__global__ __launch_bounds__(256, 1) void cvt_bf16(
    const float* __restrict__ src, u16* __restrict__ dst)
{
  const size_t i = (size_t)blockIdx.x * 256 + threadIdx.x;
  float4 a = ((const float4*)src)[2 * i];
  float4 b = ((const float4*)src)[2 * i + 1];
  ushort8 o;
  o[0] = f2b(a.x); o[1] = f2b(a.y); o[2] = f2b(a.z); o[3] = f2b(a.w);
  o[4] = f2b(b.x); o[5] = f2b(b.y); o[6] = f2b(b.z); o[7] = f2b(b.w);
  ((ushort8*)dst)[i] = o;
}

// ---------------------------------------------------------------------------
// Weight transpose+convert: W fp32 [K][N] -> Wt bf16 [N][K]. 64x64 tiles.
// ---------------------------------------------------------------------------
__global__ __launch_bounds__(256, 1) void trans_cvt_w(
    const float* __restrict__ W, u16* __restrict__ Wt)
{
  __shared__ u16 t[64][72];
  const int k0 = blockIdx.x * 64, n0 = blockIdx.y * 64;
  const int row = threadIdx.x >> 3;
  const int cs  = (threadIdx.x & 7) * 8;
#pragma unroll
  for (int p = 0; p < 2; ++p) {
    int r = row + p * 32;
    const float* Wp = W + (size_t)(k0 + r) * 1024 + n0 + cs;
    float4 a = *(const float4*)(Wp);
    float4 b = *(const float4*)(Wp + 4);
    u16* tp = &t[r][cs];
    tp[0] = f2b(a.x); tp[1] = f2b(a.y); tp[2] = f2b(a.z); tp[3] = f2b(a.w);
    tp[4] = f2b(b.x); tp[5] = f2b(b.y); tp[6] = f2b(b.z); tp[7] = f2b(b.w);
  }
  __syncthreads();
#pragma unroll
  for (int p = 0; p < 2; ++p) {
    int n = row + p * 32;
    ushort8 v;
#pragma unroll
    for (int i = 0; i < 8; ++i) v[i] = t[cs + i][n];
    *(ushort8*)(Wt + (size_t)(n0 + n) * 1024 + k0 + cs) = v;
  }
}

// ---------------------------------------------------------------------------
// bf16 MFMA GEMM: C[M][N] = A[M][K] @ Bt[N][K]^T + bias[N] (fp32 accum).
// 128x128 tile, BK=32, 256 threads / 4 waves. m97-style global_load_lds
// width-16 staging. out_f32: 1 -> fp32 stores, 0 -> bf16 stores.
// ---------------------------------------------------------------------------
__global__ __launch_bounds__(256, 1) void gemm_bf16(
    const u16* __restrict__ A, const u16* __restrict__ Bt,
    const float* __restrict__ bias, void* __restrict__ Cv,
    int M, int N, int K, int out_f32)
{
  __shared__ u16 As[128 * 32];   // [m][k] row-major, 8KB
  __shared__ u16 Bs[128 * 32];   // [n][k] row-major, 8KB
  const int tid  = threadIdx.x;
  const int wave = tid >> 6;
  const int lane = tid & 63;
  const int quad = lane >> 4;
  const int l16  = lane & 15;
  const int m0   = (wave & 1) * 64;
  const int n0   = (wave >> 1) * 64;

  const u16* Ab = A  + (size_t)blockIdx.x * 128 * K;
  const u16* Bb = Bt + (size_t)blockIdx.y * 128 * K;

  f32x4 acc[4][4];
#pragma unroll
  for (int i = 0; i < 4; ++i)
#pragma unroll
    for (int j = 0; j < 4; ++j) acc[i][j] = (f32x4){0.f, 0.f, 0.f, 0.f};

  for (int kb = 0; kb < K; kb += 32) {
    __syncthreads();               // prior iter's LDS reads done
#pragma unroll
    for (int p = 0; p < 2; ++p) {  // 512 16B segs over 256 threads
      int seg = tid + p * 256;     // = (wave*64+p*256) + lane -> base+lane*16
      int row = seg >> 2, ks = seg & 3;
      gload_lds16(Ab + (size_t)row * K + kb + ks * 8, As + seg * 8);
      gload_lds16(Bb + (size_t)row * K + kb + ks * 8, Bs + seg * 8);
    }
    __builtin_amdgcn_s_waitcnt(0); // drain vmcnt before barrier
    __syncthreads();

    bf16x8 af[4], bfr[4];
#pragma unroll
    for (int i = 0; i < 4; ++i)    // A-frag: m=lane&15, k=quad*8+j
      af[i] = *(const bf16x8*)(As + (m0 + i * 16 + l16) * 32 + quad * 8);
#pragma unroll
    for (int j = 0; j < 4; ++j)    // B-frag: n=lane&15, k=quad*8+j
      bfr[j] = *(const bf16x8*)(Bs + (n0 + j * 16 + l16) * 32 + quad * 8);
#pragma unroll
    for (int i = 0; i < 4; ++i)
#pragma unroll
      for (int j = 0; j < 4; ++j)
        acc[i][j] = __builtin_amdgcn_mfma_f32_16x16x32_bf16(
            af[i], bfr[j], acc[i][j], 0, 0, 0);
  }

  float bv[4];
#pragma unroll
  for (int j = 0; j < 4; ++j)
    bv[j] = bias[(size_t)blockIdx.y * 128 + n0 + j * 16 + l16];

  if (out_f32) {
    float* C = (float*)Cv;
#pragma unroll
    for (int i = 0; i < 4; ++i) {
      int r = blockIdx.x * 128 + m0 + i * 16 + quad * 4;   // row=quad*4+reg
#pragma unroll
      for (int j = 0; j < 4; ++j) {
        int c = blockIdx.y * 128 + n0 + j * 16 + l16;      // col=lane&15
#pragma unroll
        for (int reg = 0; reg < 4; ++reg)
          C[(size_t)(r + reg) * N + c] = acc[i][j][reg] + bv[j];
      }
    }
  } else {
    u16* C = (u16*)Cv;
#pragma unroll
    for (int i = 0; i < 4; ++i) {
      int r = blockIdx.x * 128 + m0 + i * 16 + quad * 4;
#pragma unroll
      for (int j = 0; j < 4; ++j) {
        int c = blockIdx.y * 128 + n0 + j * 16 + l16;
#pragma unroll
        for (int reg = 0; reg < 4; ++reg)
          C[(size_t)(r + reg) * N + c] = f2b(acc[i][j][reg] + bv[j]);
      }
    }
  }
}

// ---------------------------------------------------------------------------
// V transpose (bf16): V[b][s][h*64+e] -> Vt[(b*16+h)*64+e][s]  (per-head E,S)
// ---------------------------------------------------------------------------
__global__ __launch_bounds__(256, 1) void transpose_v(
    const u16* __restrict__ V, u16* __restrict__ Vt)
{
  __shared__ u16 t[64][72];
  const int s0 = blockIdx.x * 64;
  const int bh = blockIdx.y;           // b*16 + h
  const int b = bh >> 4, h = bh & 15;
  const int row = threadIdx.x >> 3;
  const int cs  = (threadIdx.x & 7) * 8;
#pragma unroll
  for (int p = 0; p < 2; ++p) {
    int s = row + p * 32;
    *(ushort8*)(&t[s][cs]) = *(const ushort8*)(
        V + ((size_t)(b * S_ + s0 + s)) * D_ + h * E_ + cs);
  }
  __syncthreads();
#pragma unroll
  for (int p = 0; p < 2; ++p) {
    int e = row + p * 32;
    ushort8 v;
#pragma unroll
    for (int i = 0; i < 8; ++i) v[i] = t[cs + i][e];
    *(ushort8*)(Vt + ((size_t)(bh * E_ + e)) * S_ + s0 + cs) = v;
  }
}

// ---------------------------------------------------------------------------
// Fused attention, softmax over HEADS, bf16 MFMA.  R14:
// R13 skeleton (32q/1024thr/16-warp, KVBLK=64, 16 compile-time iters).
// Softmax: thread=(q, 2 consec k) -> b32 LDS, conflict-free; masked points
// (k>q, head-independent) write 0x3D80 w/o exp; no max-sub (+sum==0 guard);
// tree sum. QK sub-tiles skipped when block-uniformly masked. 2 barriers.
// LDS: scf[16][32][72] + at[16][32][72] bf16 = 144KB (1 block/CU).
// ---------------------------------------------------------------------------
__global__ __launch_bounds__(1024, 4) void attn_headsoftmax(
    const u16* __restrict__ Qg,   // [B][S][D] bf16
    const u16* __restrict__ Kg,   // [B][S][D] bf16
    const u16* __restrict__ Vt,   // [B*H][E][S] bf16
    u16* __restrict__ AO)         // [B][S][D] bf16
{
  const int id   = blockIdx.x;         // 0..255; id&7 == b == XCD
  const int b    = id & 7;
  const int qt   = id >> 3;            // 0..31
  const int tid  = threadIdx.x;
  const int h    = tid >> 6;
  const int lane = tid & 63;
  const int quad = lane >> 4;
  const int l16  = lane & 15;
  const int q0   = qt * 32;

  __shared__ u16 scf[16][32][72];      // bf16 scores (72KB; 144B rows, 16B-al)
  __shared__ u16 at[16][32][72];       // bf16 attn   (72KB)

  const u16* Kh = Kg + (size_t)b * S_ * D_ + h * E_;
  const u16* Vh = Vt + ((size_t)(b * H_ + h) * E_) * S_;

  // 1/sqrt(8), correctly rounded fp32; s==0 <=> dot==0 under both forms.
  const float inv_rsq8 = 0.35355339059327373f;

  // ---- Q fragments (R7 verbatim) ----
  bf16x8 qf[2][2];
  {
    const u16* Qb = Qg + ((size_t)(b * S_ + q0)) * D_ + h * E_;
#pragma unroll
    for (int i = 0; i < 2; ++i)
#pragma unroll
      for (int c = 0; c < 2; ++c)
        qf[i][c] = *(const bf16x8*)(Qb + (size_t)(i * 16 + l16) * D_ +
                                    c * 32 + quad * 8);
  }

  f32x4 oacc[2][4];
#pragma unroll
  for (int i = 0; i < 2; ++i)
#pragma unroll
    for (int nc = 0; nc < 4; ++nc) oacc[i][nc] = (f32x4){0.f, 0.f, 0.f, 0.f};

  // softmax thread mapping: (q = tid>>5, k-chunk = (tid&31)*2)
  const int sm_q  = tid >> 5;
  const int sm_k  = (tid & 31) * 2;

  for (int kt = 0; kt < 16; ++kt) {
    const int k0 = kt * 64;
    // ---- QK^T: two 32-col sub-tiles; skip block-uniformly-masked ones ----
#pragma unroll
    for (int c2 = 0; c2 < 2; ++c2) {
      const int ks0 = k0 + c2 * 32;
      if (ks0 <= q0 + 31) {          // else fully masked: softmax writes 1/16
        const u16* Kb = Kh + (size_t)ks0 * D_;
        bf16x8 kf[2][2];
#pragma unroll
        for (int nc = 0; nc < 2; ++nc)
#pragma unroll
          for (int c = 0; c < 2; ++c)
            kf[nc][c] = *(const bf16x8*)(Kb + (size_t)(nc * 16 + l16) * D_ +
                                         c * 32 + quad * 8);
        f32x4 sacc[2][2];
#pragma unroll
        for (int i = 0; i < 2; ++i)
#pragma unroll
          for (int nc = 0; nc < 2; ++nc)
            sacc[i][nc] = (f32x4){0.f, 0.f, 0.f, 0.f};
#pragma unroll
        for (int c = 0; c < 2; ++c)
#pragma unroll
          for (int i = 0; i < 2; ++i)
#pragma unroll
            for (int nc = 0; nc < 2; ++nc)
              sacc[i][nc] = __builtin_amdgcn_mfma_f32_16x16x32_bf16(
                  qf[i][c], kf[nc][c], sacc[i][nc], 0, 0, 0);
#pragma unroll
        for (int i = 0; i < 2; ++i)
#pragma unroll
          for (int nc = 0; nc < 2; ++nc)
#pragma unroll
            for (int reg = 0; reg < 4; ++reg) {
              int qrow = i * 16 + quad * 4 + reg;  // C: row=quad*4+reg
              int kcol = nc * 16 + l16;            // C: col=lane&15
              float s = sacc[i][nc][reg] * inv_rsq8;
              if ((ks0 + kcol > q0 + qrow) || (s == 0.0f)) s = -1e9f;
              scf[h][qrow][c2 * 32 + kcol] = f2b(s);
            }
      }
    }
    __syncthreads();
    {  // ---- softmax across 16 heads; (q, 2 consec k) per thread ----
      const int qpos = q0 + sm_q;
      const int kpos = k0 + sm_k;
      int nU = qpos - kpos + 1;            // unmasked count in chunk [0..2]
      nU = nU < 0 ? 0 : (nU > 2 ? 2 : nU);
      if (nU == 0) {
        const u32 cc = 0x3D803D80u;        // bf16(1/16) x2
#pragma unroll
        for (int hh = 0; hh < 16; ++hh)
          *(u32*)&at[hh][sm_q][sm_k] = cc;
      } else {
        u32 v2[16];
#pragma unroll
        for (int hh = 0; hh < 16; ++hh)
          v2[hh] = *(const u32*)&scf[hh][sm_q][sm_k];
        u32 o2[16];
        {  // element 0 (always unmasked when nU>=1)
          float e0,e1,e2,e3,e4,e5,e6,e7,e8,e9,ea,eb,ec,ed,ee,ef;
          e0 = __expf(b2f((u16)(v2[0]  & 0xffffu)));
          e1 = __expf(b2f((u16)(v2[1]  & 0xffffu)));
          e2 = __expf(b2f((u16)(v2[2]  & 0xffffu)));
          e3 = __expf(b2f((u16)(v2[3]  & 0xffffu)));
          e4 = __expf(b2f((u16)(v2[4]  & 0xffffu)));
          e5 = __expf(b2f((u16)(v2[5]  & 0xffffu)));
          e6 = __expf(b2f((u16)(v2[6]  & 0xffffu)));
          e7 = __expf(b2f((u16)(v2[7]  & 0xffffu)));
          e8 = __expf(b2f((u16)(v2[8]  & 0xffffu)));
          e9 = __expf(b2f((u16)(v2[9]  & 0xffffu)));
          ea = __expf(b2f((u16)(v2[10] & 0xffffu)));
          eb = __expf(b2f((u16)(v2[11] & 0xffffu)));
          ec = __expf(b2f((u16)(v2[12] & 0xffffu)));
          ed = __expf(b2f((u16)(v2[13] & 0xffffu)));
          ee = __expf(b2f((u16)(v2[14] & 0xffffu)));
          ef = __expf(b2f((u16)(v2[15] & 0xffffu)));
          float sum = (((e0+e1)+(e2+e3))+((e4+e5)+(e6+e7)))
                    + (((e8+e9)+(ea+eb))+((ec+ed)+(ee+ef)));
          float inv = 1.0f / sum;
          bool z = (sum == 0.0f);          // all-quirk guard -> uniform 1/16
          o2[0]  = z ? 0x3D80u : (u32)f2b(e0 * inv);
          o2[1]  = z ? 0x3D80u : (u32)f2b(e1 * inv);
          o2[2]  = z ? 0x3D80u : (u32)f2b(e2 * inv);
          o2[3]  = z ? 0x3D80u : (u32)f2b(e3 * inv);
          o2[4]  = z ? 0x3D80u : (u32)f2b(e4 * inv);
          o2[5]  = z ? 0x3D80u : (u32)f2b(e5 * inv);
          o2[6]  = z ? 0x3D80u : (u32)f2b(e6 * inv);
          o2[7]  = z ? 0x3D80u : (u32)f2b(e7 * inv);
          o2[8]  = z ? 0x3D80u : (u32)f2b(e8 * inv);
          o2[9]  = z ? 0x3D80u : (u32)f2b(e9 * inv);
          o2[10] = z ? 0x3D80u : (u32)f2b(ea * inv);
          o2[11] = z ? 0x3D80u : (u32)f2b(eb * inv);
          o2[12] = z ? 0x3D80u : (u32)f2b(ec * inv);
          o2[13] = z ? 0x3D80u : (u32)f2b(ed * inv);
          o2[14] = z ? 0x3D80u : (u32)f2b(ee * inv);
          o2[15] = z ? 0x3D80u : (u32)f2b(ef * inv);
        }
        if (nU == 2) {  // element 1 real
          float e0,e1,e2,e3,e4,e5,e6,e7,e8,e9,ea,eb,ec,ed,ee,ef;
          e0 = __expf(b2f((u16)(v2[0]  >> 16)));
          e1 = __expf(b2f((u16)(v2[1]  >> 16)));
          e2 = __expf(b2f((u16)(v2[2]  >> 16)));
          e3 = __expf(b2f((u16)(v2[3]  >> 16)));
          e4 = __expf(b2f((u16)(v2[4]  >> 16)));
          e5 = __expf(b2f((u16)(v2[5]  >> 16)));
          e6 = __expf(b2f((u16)(v2[6]  >> 16)));
          e7 = __expf(b2f((u16)(v2[7]  >> 16)));
          e8 = __expf(b2f((u16)(v2[8]  >> 16)));
          e9 = __expf(b2f((u16)(v2[9]  >> 16)));
          ea = __expf(b2f((u16)(v2[10] >> 16)));
          eb = __expf(b2f((u16)(v2[11] >> 16)));
          ec = __expf(b2f((u16)(v2[12] >> 16)));
          ed = __expf(b2f((u16)(v2[13] >> 16)));
          ee = __expf(b2f((u16)(v2[14] >> 16)));
          ef = __expf(b2f((u16)(v2[15] >> 16)));
          float sum = (((e0+e1)+(e2+e3))+((e4+e5)+(e6+e7)))
                    + (((e8+e9)+(ea+eb))+((ec+ed)+(ee+ef)));
          float inv = 1.0f / sum;
          bool z = (sum == 0.0f);
          o2[0]  |= ((u32)(z ? 0x3D80u : f2b(e0 * inv))) << 16;
          o2[1]  |= ((u32)(z ? 0x3D80u : f2b(e1 * inv))) << 16;
          o2[2]  |= ((u32)(z ? 0x3D80u : f2b(e2 * inv))) << 16;
          o2[3]  |= ((u32)(z ? 0x3D80u : f2b(e3 * inv))) << 16;
          o2[4]  |= ((u32)(z ? 0x3D80u : f2b(e4 * inv))) << 16;
          o2[5]  |= ((u32)(z ? 0x3D80u : f2b(e5 * inv))) << 16;
          o2[6]  |= ((u32)(z ? 0x3D80u : f2b(e6 * inv))) << 16;
          o2[7]  |= ((u32)(z ? 0x3D80u : f2b(e7 * inv))) << 16;
          o2[8]  |= ((u32)(z ? 0x3D80u : f2b(e8 * inv))) << 16;
          o2[9]  |= ((u32)(z ? 0x3D80u : f2b(e9 * inv))) << 16;
          o2[10] |= ((u32)(z ? 0x3D80u : f2b(ea * inv))) << 16;
          o2[11] |= ((u32)(z ? 0x3D80u : f2b(eb * inv))) << 16;
          o2[12] |= ((u32)(z ? 0x3D80u : f2b(ec * inv))) << 16;
          o2[13] |= ((u32)(z ? 0x3D80u : f2b(ed * inv))) << 16;
          o2[14] |= ((u32)(z ? 0x3D80u : f2b(ee * inv))) << 16;
          o2[15] |= ((u32)(z ? 0x3D80u : f2b(ef * inv))) << 16;
        } else {        // element 1 masked -> 1/16
#pragma unroll
          for (int hh = 0; hh < 16; ++hh) o2[hh] |= 0x3D800000u;
        }
#pragma unroll
        for (int hh = 0; hh < 16; ++hh)
          *(u32*)&at[hh][sm_q][sm_k] = o2[hh];
      }
    }
    __syncthreads();
    // ---- PV: two 32-col sub-tiles (always full: masked attn == 1/16) ----
#pragma unroll
    for (int c2 = 0; c2 < 2; ++c2) {
      bf16x8 af[2];
#pragma unroll
      for (int i = 0; i < 2; ++i)    // A: m=q (lane&15), k=s (quad*8+jj)
        af[i] = *(const bf16x8*)(&at[h][i * 16 + l16][c2 * 32 + quad * 8]);
      const u16* Vb = Vh + k0 + c2 * 32;
      bf16x8 vf[4];
#pragma unroll
      for (int nc = 0; nc < 4; ++nc) // B: n=e (lane&15), k=s (quad*8+jj)
        vf[nc] = *(const bf16x8*)(Vb + (size_t)(nc * 16 + l16) * S_ +
                                  quad * 8);
#pragma unroll
      for (int i = 0; i < 2; ++i)
#pragma unroll
        for (int nc = 0; nc < 4; ++nc)
          oacc[i][nc] = __builtin_amdgcn_mfma_f32_16x16x32_bf16(
              af[i], vf[nc], oacc[i][nc], 0, 0, 0);
    }
    // no barrier: next QK writes scf (last read pre-2nd-barrier); `at`
    // reuse is ordered by next iteration's post-QK barrier.
  }

  u16* Ob = AO + ((size_t)(b * S_ + q0)) * D_ + h * E_;
#pragma unroll
  for (int i = 0; i < 2; ++i)
#pragma unroll
    for (int nc = 0; nc < 4; ++nc)
#pragma unroll
      for (int reg = 0; reg < 4; ++reg) {
        int qrow = i * 16 + quad * 4 + reg;
        int e    = nc * 16 + l16;
        Ob[(size_t)qrow * D_ + e] = f2b(oacc[i][nc][reg]);
      }
}

// ---------------------------------------------------------------------------
extern "C" void kernel_launch(void* const* d_in, const int* in_sizes, int n_in,
                              void* d_out, int out_size, void* d_ws,
                              size_t ws_size, hipStream_t stream)
{
  const float* X1 = (const float*)d_in[0];
  const float* X2 = (const float*)d_in[1];
  const float* Wq = (const float*)d_in[2];
  const float* bq = (const float*)d_in[3];
  const float* Wk = (const float*)d_in[4];
  const float* bk = (const float*)d_in[5];
  const float* Wv = (const float*)d_in[6];
  const float* bv = (const float*)d_in[7];
  const float* Wo = (const float*)d_in[8];
  const float* bo = (const float*)d_in[9];

  // Workspace (u16 units): X1b,X2b 8M; Wt 1M x4; Qb,Kb,Vb,Vtb 8M. AO aliases
  // Vb (dead after transpose_v). Total 44M u16 = 88MB.
  u16* X1b = (u16*)d_ws;
  u16* X2b = X1b + (8u << 20);
  u16* WtQ = X2b + (8u << 20);
  u16* WtK = WtQ + (1u << 20);
  u16* WtV = WtK + (1u << 20);
  u16* WtO = WtV + (1u << 20);
  u16* Qb  = WtO + (1u << 20);
  u16* Kb  = Qb + (8u << 20);
  u16* Vb  = Kb + (8u << 20);
  u16* Vtb = Vb + (8u << 20);
  u16* AOb = Vb;  // alias

  cvt_bf16<<<4096, 256, 0, stream>>>(X1, X1b);
  cvt_bf16<<<4096, 256, 0, stream>>>(X2, X2b);

  dim3 tg(16, 16);
  trans_cvt_w<<<tg, 256, 0, stream>>>(Wq, WtQ);
  trans_cvt_w<<<tg, 256, 0, stream>>>(Wk, WtK);
  trans_cvt_w<<<tg, 256, 0, stream>>>(Wv, WtV);
  trans_cvt_w<<<tg, 256, 0, stream>>>(Wo, WtO);

  dim3 gg(64, 8);  // (M/128, N/128)
  gemm_bf16<<<gg, 256, 0, stream>>>(X1b, WtQ, bq, Qb, 8192, 1024, 1024, 0);
  gemm_bf16<<<gg, 256, 0, stream>>>(X2b, WtK, bk, Kb, 8192, 1024, 1024, 0);
  gemm_bf16<<<gg, 256, 0, stream>>>(X2b, WtV, bv, Vb, 8192, 1024, 1024, 0);

  transpose_v<<<dim3(16, 128), 256, 0, stream>>>(Vb, Vtb);

  attn_headsoftmax<<<dim3(256), 1024, 0, stream>>>(Qb, Kb, Vtb, AOb);

  // Output fp32 (reference returns float32).
  gemm_bf16<<<gg, 256, 0, stream>>>(AOb, WtO, bo, d_out, 8192, 1024, 1024, 1);
}